// Round 6
// baseline (563.965 us; speedup 1.0000x reference)
//
#include <hip/hip_runtime.h>

#define N_NODES 100000
#define N_EDGES 3200000
#define D_NODE  64
#define D_EDGE  16
#define OUT_DIM 64

#define FPSCALE     524288.0f           // 2^19
#define INV_FPSCALE 1.9073486328125e-6f // 2^-19

// net is padded: one packed i64 accumulator per node, 128B apart (16 i64 slots).
// Tests the same-cacheline-serialization hypothesis for the atomic ceiling.
#define NET_STRIDE 16

// ---------------- prep: compact V_node[:, :2] + zero packed net ----------------
__global__ __launch_bounds__(256) void prep_kernel(const float* __restrict__ V_node,
                                                   float* __restrict__ V2,
                                                   long long* __restrict__ net) {
    int n = blockIdx.x * 256 + threadIdx.x;
    if (n < N_NODES) {
        const float2 v = *reinterpret_cast<const float2*>(V_node + (size_t)n * D_NODE);
        reinterpret_cast<float2*>(V2)[n] = v;
        net[(size_t)n * NET_STRIDE] = 0LL;
    }
}

// ---------------- edge phase: I_pred + packed fixed-point scatter-add ----------------
__global__ __launch_bounds__(256) void edge_kernel(const int* __restrict__ senders,
                                                   const int* __restrict__ receivers,
                                                   const float* __restrict__ EF,
                                                   const float* __restrict__ V2,
                                                   const float* __restrict__ W_res,
                                                   const float* __restrict__ b_res,
                                                   float* __restrict__ I_pred_out,
                                                   long long* __restrict__ net) {
    int e = blockIdx.x * 256 + threadIdx.x;
    if (e >= N_EDGES) return;

    // uniform params — scalar loads, overlap with vector gathers below
    float b0 = b_res[0], b1 = b_res[1];
    float w[20][2];
    #pragma unroll
    for (int k = 0; k < 20; ++k) { w[k][0] = W_res[k * 2 + 0]; w[k][1] = W_res[k * 2 + 1]; }

    int s = senders[e];
    int r = receivers[e];
    float2 vr = reinterpret_cast<const float2*>(V2)[r];
    float2 vs = reinterpret_cast<const float2*>(V2)[s];
    float vre = vr.x - vs.x;
    float vim = vr.y - vs.y;
    const float4* EF4 = reinterpret_cast<const float4*>(EF) + (size_t)e * 4;
    float4 f0 = EF4[0], f1 = EF4[1], f2 = EF4[2], f3 = EF4[3];
    float G = f0.x, B = f0.y;
    float ire = G * vre - B * vim;
    float iim = G * vim + B * vre;
    float ei[20] = {vre, vim,
                    f0.x, f0.y, f0.z, f0.w,
                    f1.x, f1.y, f1.z, f1.w,
                    f2.x, f2.y, f2.z, f2.w,
                    f3.x, f3.y, f3.z, f3.w,
                    ire, iim};
    float p0 = ire + b0;
    float p1 = iim + b1;
    #pragma unroll
    for (int k = 0; k < 20; ++k) {
        p0 = fmaf(ei[k], w[k][0], p0);
        p1 = fmaf(ei[k], w[k][1], p1);
    }

    // I_pred store (nontemporal: never re-read, keep L2 for V2)
    float2 ip = make_float2(p0, p1);
    __builtin_nontemporal_store(__builtin_bit_cast(unsigned long long, ip),
                                reinterpret_cast<unsigned long long*>(I_pred_out) + e);

    // packed exact fixed-point: v = f1*2^32 + f0 (sign-extended ADD).
    // Decode identity: lo = S0 exactly (int32); hi = S1 + [S0<0].
    long long fx0 = (long long)__float2int_rn(p0 * FPSCALE);
    long long fx1 = (long long)__float2int_rn(p1 * FPSCALE);
    long long pk = (fx1 << 32) + fx0;
    atomicAdd((unsigned long long*)(net + (size_t)r * NET_STRIDE), (unsigned long long)pk);
    atomicAdd((unsigned long long*)(net + (size_t)s * NET_STRIDE), (unsigned long long)(-pk));
}

// ---------------- node phase: out = relu([V_node | net] @ W_node + b) ----------------
#define A_STRIDE 68   // 66 used + pad -> rows stay 16B aligned (68 % 4 == 0)

__global__ __launch_bounds__(256) void node_kernel(const float* __restrict__ V_node,
                                                   const long long* __restrict__ net,
                                                   const float* __restrict__ W_node,
                                                   const float* __restrict__ b_node,
                                                   float* __restrict__ out) {
    __shared__ __align__(16) float Wl[66 * 64];
    __shared__ __align__(16) float Al[64 * A_STRIDE];
    const int t  = threadIdx.x;
    const int n0 = blockIdx.x * 64;

    // stage W (66x64) into LDS, coalesced
    for (int i = t; i < 66 * 64; i += 256) Wl[i] = W_node[i];

    // stage A tile: 64 nodes x 64 V-features, float4 fully coalesced
    {
        const float4* Vg  = reinterpret_cast<const float4*>(V_node);
        float4*       Al4 = reinterpret_cast<float4*>(Al);
        #pragma unroll
        for (int q = 0; q < 4; ++q) {
            int f    = t + 256 * q;       // 0..1023 float4s in tile
            int node = f >> 4;
            int c4   = f & 15;
            int ng   = n0 + node;
            float4 v = (ng < N_NODES) ? Vg[(size_t)ng * 16 + c4]
                                      : make_float4(0.f, 0.f, 0.f, 0.f);
            Al4[node * (A_STRIDE / 4) + c4] = v;
        }
    }
    // stage + decode packed net_current (1 node per thread)
    if (t < 64) {
        int ng = n0 + t;
        float c0 = 0.f, c1 = 0.f;
        if (ng < N_NODES) {
            long long acc = net[(size_t)ng * NET_STRIDE];
            int s0 = (int)(unsigned int)(acc & 0xffffffffLL);
            int s1 = (int)(acc >> 32) + (s0 < 0 ? 1 : 0);
            c0 = (float)s0 * INV_FPSCALE;
            c1 = (float)s1 * INV_FPSCALE;
        }
        Al[t * A_STRIDE + 64] = c0;
        Al[t * A_STRIDE + 65] = c1;
    }
    __syncthreads();

    const int tcol = t & 15;   // 16 col-groups of 4
    const int trow = t >> 4;   // 16 row-groups of 4 nodes
    float4 bj = reinterpret_cast<const float4*>(b_node)[tcol];
    float4 acc[4];
    #pragma unroll
    for (int i = 0; i < 4; ++i) acc[i] = bj;

    const float4* Wl4 = reinterpret_cast<const float4*>(Wl);
    // main K loop in chunks of 4, A rows read as float4 (fewer LDS ops)
    #pragma unroll 4
    for (int kc = 0; kc < 64; kc += 4) {
        float a[4][4];
        #pragma unroll
        for (int i = 0; i < 4; ++i) {
            float4 av = *reinterpret_cast<const float4*>(&Al[(trow * 4 + i) * A_STRIDE + kc]);
            a[i][0] = av.x; a[i][1] = av.y; a[i][2] = av.z; a[i][3] = av.w;
        }
        #pragma unroll
        for (int kk = 0; kk < 4; ++kk) {
            float4 wv = Wl4[(kc + kk) * 16 + tcol];
            #pragma unroll
            for (int i = 0; i < 4; ++i) {
                acc[i].x = fmaf(a[i][kk], wv.x, acc[i].x);
                acc[i].y = fmaf(a[i][kk], wv.y, acc[i].y);
                acc[i].z = fmaf(a[i][kk], wv.z, acc[i].z);
                acc[i].w = fmaf(a[i][kk], wv.w, acc[i].w);
            }
        }
    }
    // tail: k = 64, 65 (net_current columns)
    #pragma unroll
    for (int k = 64; k < 66; ++k) {
        float4 wv = Wl4[k * 16 + tcol];
        #pragma unroll
        for (int i = 0; i < 4; ++i) {
            float a = Al[(trow * 4 + i) * A_STRIDE + k];
            acc[i].x = fmaf(a, wv.x, acc[i].x);
            acc[i].y = fmaf(a, wv.y, acc[i].y);
            acc[i].z = fmaf(a, wv.z, acc[i].z);
            acc[i].w = fmaf(a, wv.w, acc[i].w);
        }
    }

    #pragma unroll
    for (int i = 0; i < 4; ++i) {
        int ng = n0 + trow * 4 + i;
        if (ng < N_NODES) {
            float4 o = acc[i];
            o.x = fmaxf(o.x, 0.f);
            o.y = fmaxf(o.y, 0.f);
            o.z = fmaxf(o.z, 0.f);
            o.w = fmaxf(o.w, 0.f);
            reinterpret_cast<float4*>(out)[(size_t)ng * 16 + tcol] = o;
        }
    }
}

extern "C" void kernel_launch(void* const* d_in, const int* in_sizes, int n_in,
                              void* d_out, int out_size, void* d_ws, size_t ws_size,
                              hipStream_t stream) {
    const float* V_node    = (const float*)d_in[0];
    const int*   senders   = (const int*)  d_in[1];
    const int*   receivers = (const int*)  d_in[2];
    const float* EF        = (const float*)d_in[3];
    const float* W_res     = (const float*)d_in[4];
    const float* b_res     = (const float*)d_in[5];
    const float* W_node    = (const float*)d_in[6];
    const float* b_node    = (const float*)d_in[7];

    float* out   = (float*)d_out;
    float* Vout  = out;                                   // N_NODES * 64
    float* Ipred = out + (size_t)N_NODES * OUT_DIM;       // N_EDGES * 2

    long long* net = (long long*)d_ws;                    // N_NODES * 128B padded
    float*     V2  = (float*)(net + (size_t)N_NODES * NET_STRIDE); // N_NODES * 2 floats

    prep_kernel<<<(N_NODES + 255) / 256, 256, 0, stream>>>(V_node, V2, net);
    edge_kernel<<<(N_EDGES + 255) / 256, 256, 0, stream>>>(senders, receivers, EF, V2,
                                                           W_res, b_res, Ipred, net);
    node_kernel<<<(N_NODES + 63) / 64, 256, 0, stream>>>(V_node, net, W_node, b_node, Vout);
}

// Round 7
// 556.513 us; speedup vs baseline: 1.0134x; 1.0134x over previous
//
#include <hip/hip_runtime.h>

#define N_NODES 100000
#define N_EDGES 3200000
#define D_NODE  64
#define D_EDGE  16
#define OUT_DIM 64
#define NXCD    8

#define FPSCALE     524288.0f           // 2^19
#define INV_FPSCALE 1.9073486328125e-6f // 2^-19

// Physical XCD id of the CU this wave runs on (uniform per workgroup).
__device__ __forceinline__ int xcc_id() {
    int v;
    asm volatile("s_getreg_b32 %0, hwreg(HW_REG_XCC_ID)" : "=s"(v));
    return v & (NXCD - 1);
}

// ---------------- prep: compact V_node[:, :2] + zero 8 per-XCD net copies ----------------
__global__ __launch_bounds__(256) void prep_kernel(const float* __restrict__ V_node,
                                                   float* __restrict__ V2,
                                                   long long* __restrict__ net) {
    int i = blockIdx.x * 256 + threadIdx.x;
    if (i < N_NODES * NXCD) net[i] = 0LL;       // zero all 8 copies
    if (i < N_NODES) {
        const float2 v = *reinterpret_cast<const float2*>(V_node + (size_t)i * D_NODE);
        reinterpret_cast<float2*>(V2)[i] = v;
    }
}

// ---------------- edge phase: I_pred + XCD-local packed fixed-point scatter-add ----------------
__global__ __launch_bounds__(256) void edge_kernel(const int* __restrict__ senders,
                                                   const int* __restrict__ receivers,
                                                   const float* __restrict__ EF,
                                                   const float* __restrict__ V2,
                                                   const float* __restrict__ W_res,
                                                   const float* __restrict__ b_res,
                                                   float* __restrict__ I_pred_out,
                                                   long long* __restrict__ net) {
    int e = blockIdx.x * 256 + threadIdx.x;
    if (e >= N_EDGES) return;

    // this XCD's private accumulator copy (workgroup-scope atomics execute in XCD L2)
    long long* mycopy = net + (size_t)xcc_id() * N_NODES;

    // uniform params — scalar loads, overlap with vector gathers below
    float b0 = b_res[0], b1 = b_res[1];
    float w[20][2];
    #pragma unroll
    for (int k = 0; k < 20; ++k) { w[k][0] = W_res[k * 2 + 0]; w[k][1] = W_res[k * 2 + 1]; }

    int s = senders[e];
    int r = receivers[e];
    float2 vr = reinterpret_cast<const float2*>(V2)[r];
    float2 vs = reinterpret_cast<const float2*>(V2)[s];
    float vre = vr.x - vs.x;
    float vim = vr.y - vs.y;
    const float4* EF4 = reinterpret_cast<const float4*>(EF) + (size_t)e * 4;
    float4 f0 = EF4[0], f1 = EF4[1], f2 = EF4[2], f3 = EF4[3];
    float G = f0.x, B = f0.y;
    float ire = G * vre - B * vim;
    float iim = G * vim + B * vre;
    float ei[20] = {vre, vim,
                    f0.x, f0.y, f0.z, f0.w,
                    f1.x, f1.y, f1.z, f1.w,
                    f2.x, f2.y, f2.z, f2.w,
                    f3.x, f3.y, f3.z, f3.w,
                    ire, iim};
    float p0 = ire + b0;
    float p1 = iim + b1;
    #pragma unroll
    for (int k = 0; k < 20; ++k) {
        p0 = fmaf(ei[k], w[k][0], p0);
        p1 = fmaf(ei[k], w[k][1], p1);
    }

    // I_pred store (nontemporal: never re-read, keep L2 for V2/net copies)
    float2 ip = make_float2(p0, p1);
    __builtin_nontemporal_store(__builtin_bit_cast(unsigned long long, ip),
                                reinterpret_cast<unsigned long long*>(I_pred_out) + e);

    // packed exact fixed-point: v = f1*2^32 + f0 (sign-extended ADD).
    // Decode identity: lo = S0 exactly (int32); hi = S1 + [S0<0].
    long long fx0 = (long long)__float2int_rn(p0 * FPSCALE);
    long long fx1 = (long long)__float2int_rn(p1 * FPSCALE);
    long long pk = (fx1 << 32) + fx0;
    __hip_atomic_fetch_add((unsigned long long*)(mycopy + r), (unsigned long long)pk,
                           __ATOMIC_RELAXED, __HIP_MEMORY_SCOPE_WORKGROUP);
    __hip_atomic_fetch_add((unsigned long long*)(mycopy + s), (unsigned long long)(-pk),
                           __ATOMIC_RELAXED, __HIP_MEMORY_SCOPE_WORKGROUP);
}

// ---------------- node phase: out = relu([V_node | net] @ W_node + b) ----------------
#define A_STRIDE 68   // 66 used + pad -> rows stay 16B aligned (68 % 4 == 0)

__global__ __launch_bounds__(256) void node_kernel(const float* __restrict__ V_node,
                                                   const long long* __restrict__ net,
                                                   const float* __restrict__ W_node,
                                                   const float* __restrict__ b_node,
                                                   float* __restrict__ out) {
    __shared__ __align__(16) float Wl[66 * 64];
    __shared__ __align__(16) float Al[64 * A_STRIDE];
    const int t  = threadIdx.x;
    const int n0 = blockIdx.x * 64;

    // stage W (66x64) into LDS, coalesced
    for (int i = t; i < 66 * 64; i += 256) Wl[i] = W_node[i];

    // stage A tile: 64 nodes x 64 V-features, float4 fully coalesced
    {
        const float4* Vg  = reinterpret_cast<const float4*>(V_node);
        float4*       Al4 = reinterpret_cast<float4*>(Al);
        #pragma unroll
        for (int q = 0; q < 4; ++q) {
            int f    = t + 256 * q;       // 0..1023 float4s in tile
            int node = f >> 4;
            int c4   = f & 15;
            int ng   = n0 + node;
            float4 v = (ng < N_NODES) ? Vg[(size_t)ng * 16 + c4]
                                      : make_float4(0.f, 0.f, 0.f, 0.f);
            Al4[node * (A_STRIDE / 4) + c4] = v;
        }
    }
    // stage + decode packed net_current: sum the 8 per-XCD partial copies (exact int64)
    if (t < 64) {
        int ng = n0 + t;
        float c0 = 0.f, c1 = 0.f;
        if (ng < N_NODES) {
            long long acc = 0;
            #pragma unroll
            for (int x = 0; x < NXCD; ++x) acc += net[(size_t)x * N_NODES + ng];
            int s0 = (int)(unsigned int)(acc & 0xffffffffLL);
            int s1 = (int)(acc >> 32) + (s0 < 0 ? 1 : 0);
            c0 = (float)s0 * INV_FPSCALE;
            c1 = (float)s1 * INV_FPSCALE;
        }
        Al[t * A_STRIDE + 64] = c0;
        Al[t * A_STRIDE + 65] = c1;
    }
    __syncthreads();

    const int tcol = t & 15;   // 16 col-groups of 4
    const int trow = t >> 4;   // 16 row-groups of 4 nodes
    float4 bj = reinterpret_cast<const float4*>(b_node)[tcol];
    float4 acc[4];
    #pragma unroll
    for (int i = 0; i < 4; ++i) acc[i] = bj;

    const float4* Wl4 = reinterpret_cast<const float4*>(Wl);
    // main K loop in chunks of 4, A rows read as float4 (fewer LDS ops)
    #pragma unroll 4
    for (int kc = 0; kc < 64; kc += 4) {
        float a[4][4];
        #pragma unroll
        for (int i = 0; i < 4; ++i) {
            float4 av = *reinterpret_cast<const float4*>(&Al[(trow * 4 + i) * A_STRIDE + kc]);
            a[i][0] = av.x; a[i][1] = av.y; a[i][2] = av.z; a[i][3] = av.w;
        }
        #pragma unroll
        for (int kk = 0; kk < 4; ++kk) {
            float4 wv = Wl4[(kc + kk) * 16 + tcol];
            #pragma unroll
            for (int i = 0; i < 4; ++i) {
                acc[i].x = fmaf(a[i][kk], wv.x, acc[i].x);
                acc[i].y = fmaf(a[i][kk], wv.y, acc[i].y);
                acc[i].z = fmaf(a[i][kk], wv.z, acc[i].z);
                acc[i].w = fmaf(a[i][kk], wv.w, acc[i].w);
            }
        }
    }
    // tail: k = 64, 65 (net_current columns)
    #pragma unroll
    for (int k = 64; k < 66; ++k) {
        float4 wv = Wl4[k * 16 + tcol];
        #pragma unroll
        for (int i = 0; i < 4; ++i) {
            float a = Al[(trow * 4 + i) * A_STRIDE + k];
            acc[i].x = fmaf(a, wv.x, acc[i].x);
            acc[i].y = fmaf(a, wv.y, acc[i].y);
            acc[i].z = fmaf(a, wv.z, acc[i].z);
            acc[i].w = fmaf(a, wv.w, acc[i].w);
        }
    }

    #pragma unroll
    for (int i = 0; i < 4; ++i) {
        int ng = n0 + trow * 4 + i;
        if (ng < N_NODES) {
            float4 o = acc[i];
            o.x = fmaxf(o.x, 0.f);
            o.y = fmaxf(o.y, 0.f);
            o.z = fmaxf(o.z, 0.f);
            o.w = fmaxf(o.w, 0.f);
            reinterpret_cast<float4*>(out)[(size_t)ng * 16 + tcol] = o;
        }
    }
}

extern "C" void kernel_launch(void* const* d_in, const int* in_sizes, int n_in,
                              void* d_out, int out_size, void* d_ws, size_t ws_size,
                              hipStream_t stream) {
    const float* V_node    = (const float*)d_in[0];
    const int*   senders   = (const int*)  d_in[1];
    const int*   receivers = (const int*)  d_in[2];
    const float* EF        = (const float*)d_in[3];
    const float* W_res     = (const float*)d_in[4];
    const float* b_res     = (const float*)d_in[5];
    const float* W_node    = (const float*)d_in[6];
    const float* b_node    = (const float*)d_in[7];

    float* out   = (float*)d_out;
    float* Vout  = out;                                   // N_NODES * 64
    float* Ipred = out + (size_t)N_NODES * OUT_DIM;       // N_EDGES * 2

    long long* net = (long long*)d_ws;                    // 8 copies x N_NODES packed i64
    float*     V2  = (float*)(net + (size_t)NXCD * N_NODES); // N_NODES * 2 floats

    prep_kernel<<<(N_NODES * NXCD + 255) / 256, 256, 0, stream>>>(V_node, V2, net);
    edge_kernel<<<(N_EDGES + 255) / 256, 256, 0, stream>>>(senders, receivers, EF, V2,
                                                           W_res, b_res, Ipred, net);
    node_kernel<<<(N_NODES + 63) / 64, 256, 0, stream>>>(V_node, net, W_node, b_node, Vout);
}